// Round 3
// baseline (330.566 us; speedup 1.0000x reference)
//
#include <hip/hip_runtime.h>
#include <math.h>

// ---------------------------------------------------------------------------
// ArithmeticNps: B=16384, CV=128, CR=64, NR=16, CM_RULE=128
// Plan:
//   setup_kernel : zero bucket counts; precompute read1[16][32],
//                  read2_all[16][2][16], w1ope[3][32] (write1 row for the
//                  operator encoding, which has only 3 possible values).
//   stage1_kernel: one wave per element. Encoder MLPs, write1, attent1
//                  argmax -> idx_r, write2/attent2 -> idx_p/idx_c,
//                  var_pc (256) to ws, push element into rule bucket.
//   stage2_kernel: per (rule, chunk-of-32-elements) block: fp32 GEMMs
//                  (32x256 @ 256x128 relu, 32x128 @ 128x128) + fused decoder
//                  (128->64 relu -> 1). Weights L1/L2 resident.
// ---------------------------------------------------------------------------

__global__ __launch_bounds__(256) void setup_kernel(
    const float* __restrict__ rules_emb, const float* __restrict__ s1_k_w,
    const float* __restrict__ s1_k_b,   const float* __restrict__ s2_k_w,
    const float* __restrict__ s2_k_b,   const float* __restrict__ enc_opr_w1,
    const float* __restrict__ enc_opr_b1, const float* __restrict__ enc_opr_w2,
    const float* __restrict__ enc_opr_b2, const float* __restrict__ s1_q_w,
    const float* __restrict__ s1_q_b,
    int* __restrict__ cnt, float* __restrict__ read1,
    float* __restrict__ read2_all, float* __restrict__ w1ope)
{
    const int t = threadIdx.x;
    if (t < 16) cnt[t] = 0;

    __shared__ float ope_s[3 * 128];
    for (int idx = t; idx < 3 * 128; idx += 256) {
        int v = idx >> 7, c = idx & 127;
        float o = enc_opr_b2[c];
        for (int j = 0; j < 64; ++j) {
            float h = fmaxf(enc_opr_w1[v * 64 + j] + enc_opr_b1[j], 0.f);
            o = fmaf(h, enc_opr_w2[j * 128 + c], o);
        }
        ope_s[idx] = o;
    }
    __syncthreads();

    // w1ope[v][m] = write1 row for hidden slot k=2 given operator v
    for (int idx = t; idx < 3 * 32; idx += 256) {
        int v = idx >> 5, m = idx & 31;
        float acc = s1_q_b[m];
        for (int c = 0; c < 128; ++c)
            acc = fmaf(ope_s[v * 128 + c], s1_q_w[c * 32 + m], acc);
        w1ope[idx] = acc;
    }
    // read1[n][m]
    for (int idx = t; idx < 16 * 32; idx += 256) {
        int n = idx >> 5, m = idx & 31;
        float acc = s1_k_b[idx];
        for (int r = 0; r < 64; ++r)
            acc = fmaf(rules_emb[n * 64 + r], s1_k_w[(n * 64 + r) * 32 + m], acc);
        read1[idx] = acc;
    }
    // read2_all[r][n][m]
    for (int idx = t; idx < 16 * 2 * 16; idx += 256) {
        int r = idx >> 5, n = (idx >> 4) & 1, m = idx & 15;
        float acc = s2_k_b[n * 16 + m];
        for (int j = 0; j < 64; ++j)
            acc = fmaf(rules_emb[r * 64 + j], s2_k_w[(n * 64 + j) * 16 + m], acc);
        read2_all[idx] = acc;
    }
}

__global__ __launch_bounds__(256) void stage1_kernel(
    const float* __restrict__ op1, const float* __restrict__ op2,
    const int* __restrict__ opr,
    const float* __restrict__ enc_op_w1, const float* __restrict__ enc_op_b1,
    const float* __restrict__ enc_op_w2, const float* __restrict__ enc_op_b2,
    const float* __restrict__ s1_q_w,   const float* __restrict__ s1_q_b,
    const float* __restrict__ s2_q_w,   const float* __restrict__ s2_q_b,
    const float* __restrict__ read1,    const float* __restrict__ read2_all,
    const float* __restrict__ w1ope,
    int* __restrict__ cnt, int* __restrict__ bucket,
    float* __restrict__ var_pc, int Btot)
{
    const int lane = threadIdx.x & 63;
    const int wid  = threadIdx.x >> 6;          // 0..3 (wave in block)
    const int elem = blockIdx.x * 4 + wid;

    __shared__ float hid_s[4][2][128];
    __shared__ float w1l_s[4][2][32];
    __shared__ float w2l_s[4][2][16];

    const float o1 = op1[elem];
    const float o2 = op2[elem];
    const int   op = opr[elem];

    // encoder hidden (64) for each operand; lane holds h[lane]
    float h1 = fmaxf(fmaf(o1, enc_op_w1[lane], enc_op_b1[lane]), 0.f);
    float h2 = fmaxf(fmaf(o2, enc_op_w1[lane], enc_op_w1[64 + lane] + enc_op_b1[lane]), 0.f);

    // x1e, x2e: lane owns cols {lane, lane+64}
    float x1a = enc_op_b2[lane],      x1b = enc_op_b2[64 + lane];
    float x2a = x1a,                  x2b = x1b;
    #pragma unroll 8
    for (int k = 0; k < 64; ++k) {
        float hk1 = __shfl(h1, k);
        float hk2 = __shfl(h2, k);
        float wa  = enc_op_w2[k * 128 + lane];
        float wb  = enc_op_w2[k * 128 + 64 + lane];
        x1a = fmaf(hk1, wa, x1a);  x1b = fmaf(hk1, wb, x1b);
        x2a = fmaf(hk2, wa, x2a);  x2b = fmaf(hk2, wb, x2b);
    }
    hid_s[wid][0][lane] = x1a;  hid_s[wid][0][64 + lane] = x1b;
    hid_s[wid][1][lane] = x2a;  hid_s[wid][1][64 + lane] = x2b;
    __syncthreads();

    // write1 rows k=0,1: lane -> (k = lane>>5, m = lane&31)
    {
        int k = lane >> 5, m = lane & 31;
        float acc = s1_q_b[m];
        #pragma unroll 8
        for (int c = 0; c < 128; ++c)
            acc = fmaf(hid_s[wid][k][c], s1_q_w[c * 32 + m], acc);
        w1l_s[wid][k][m] = acc;
    }
    __syncthreads();

    // attent1 scores on lanes 0..47 (lane = n*3+k = flat index)
    float score = -INFINITY;
    if (lane < 48) {
        int n = lane / 3, k = lane - n * 3;
        const float* w1row = (k < 2) ? &w1l_s[wid][k][0] : &w1ope[op * 32];
        float acc = 0.f;
        #pragma unroll 8
        for (int m = 0; m < 32; ++m)
            acc = fmaf(read1[n * 32 + m], w1row[m], acc);
        score = acc;
    }
    // wave argmax, first occurrence on ties
    float bval = score;
    int   best = lane;
    #pragma unroll
    for (int off = 32; off; off >>= 1) {
        float ov = __shfl_down(bval, off);
        int   oi = __shfl_down(best, off);
        if (ov > bval || (ov == bval && oi < best)) { bval = ov; best = oi; }
    }
    best = __shfl(best, 0);
    const int idx_r = best / 3;

    // write2: lanes 0..31 -> (n = lane>>4, m = lane&15)
    if (lane < 32) {
        int n = lane >> 4, m = lane & 15;
        float acc = s2_q_b[n * 16 + m];
        #pragma unroll 8
        for (int c = 0; c < 128; ++c)
            acc = fmaf(hid_s[wid][n][c], s2_q_w[(n * 128 + c) * 16 + m], acc);
        w2l_s[wid][n][m] = acc;
    }
    __syncthreads();

    // attent2 (computed redundantly on all lanes; tiny)
    const float* r2 = &read2_all[idx_r * 32];
    float a00 = 0.f, a01 = 0.f, a10 = 0.f, a11 = 0.f;
    #pragma unroll
    for (int m = 0; m < 16; ++m) {
        float w20 = w2l_s[wid][0][m], w21 = w2l_s[wid][1][m];
        a00 = fmaf(r2[m],      w20, a00);  a01 = fmaf(r2[m],      w21, a01);
        a10 = fmaf(r2[16 + m], w20, a10);  a11 = fmaf(r2[16 + m], w21, a11);
    }
    const int idx_p = (a01 > a00) ? 1 : 0;   // first-occurrence argmax over 2
    const int idx_c = (a11 > a10) ? 1 : 0;

    float* vp = &var_pc[(size_t)elem * 256];
    vp[lane]       = hid_s[wid][idx_p][lane];
    vp[64 + lane]  = hid_s[wid][idx_p][64 + lane];
    vp[128 + lane] = hid_s[wid][idx_c][lane];
    vp[192 + lane] = hid_s[wid][idx_c][64 + lane];

    if (lane == 0) {
        int pos = atomicAdd(&cnt[idx_r], 1);
        bucket[idx_r * Btot + pos] = elem;
    }
}

#define TB 32   // elements per stage2 block

__global__ __launch_bounds__(256) void stage2_kernel(
    const float* __restrict__ rule_W1, const float* __restrict__ rule_b1,
    const float* __restrict__ rule_W2, const float* __restrict__ rule_b2,
    const float* __restrict__ dec_w1,  const float* __restrict__ dec_b1,
    const float* __restrict__ dec_w2,  const float* __restrict__ dec_b2,
    const int* __restrict__ cnt, const int* __restrict__ bucket,
    const float* __restrict__ var_pc, float* __restrict__ out, int Btot)
{
    const int rule  = blockIdx.y;
    const int start = blockIdx.x * TB;
    const int count = cnt[rule];
    if (start >= count) return;
    const int nelem = min(TB, count - start);
    const int tid   = threadIdx.x;

    __shared__ float A[TB][260];   // var_pc rows; later reused for 'out' rows
    __shared__ float H[TB][132];   // relu hidden
    __shared__ int   gi_s[TB];

    if (tid < TB) gi_s[tid] = (tid < nelem) ? bucket[rule * Btot + start + tid] : 0;
    __syncthreads();

    for (int idx = tid; idx < TB * 64; idx += 256) {
        int e = idx >> 6, v = idx & 63;
        const float4 f = *(const float4*)&var_pc[(size_t)gi_s[e] * 256 + v * 4];
        A[e][v * 4] = f.x; A[e][v * 4 + 1] = f.y; A[e][v * 4 + 2] = f.z; A[e][v * 4 + 3] = f.w;
    }
    __syncthreads();

    const int colg = tid & 15;      // cols colg*8 .. +8
    const int rowg = tid >> 4;      // rows rowg*2 .. +2

    // ---- GEMM1: h = relu(A(32x256) @ W1(256x128) + b1)
    const float* W1  = &rule_W1[(size_t)rule * 256 * 128 + colg * 8];
    const float* b1p = &rule_b1[rule * 128 + colg * 8];
    float acc[2][8];
    #pragma unroll
    for (int j = 0; j < 8; ++j) { acc[0][j] = b1p[j]; acc[1][j] = b1p[j]; }
    #pragma unroll 4
    for (int k = 0; k < 256; ++k) {
        float a0 = A[rowg * 2][k], a1 = A[rowg * 2 + 1][k];
        const float4 wa = *(const float4*)&W1[k * 128];
        const float4 wb = *(const float4*)&W1[k * 128 + 4];
        acc[0][0] = fmaf(a0, wa.x, acc[0][0]); acc[1][0] = fmaf(a1, wa.x, acc[1][0]);
        acc[0][1] = fmaf(a0, wa.y, acc[0][1]); acc[1][1] = fmaf(a1, wa.y, acc[1][1]);
        acc[0][2] = fmaf(a0, wa.z, acc[0][2]); acc[1][2] = fmaf(a1, wa.z, acc[1][2]);
        acc[0][3] = fmaf(a0, wa.w, acc[0][3]); acc[1][3] = fmaf(a1, wa.w, acc[1][3]);
        acc[0][4] = fmaf(a0, wb.x, acc[0][4]); acc[1][4] = fmaf(a1, wb.x, acc[1][4]);
        acc[0][5] = fmaf(a0, wb.y, acc[0][5]); acc[1][5] = fmaf(a1, wb.y, acc[1][5]);
        acc[0][6] = fmaf(a0, wb.z, acc[0][6]); acc[1][6] = fmaf(a1, wb.z, acc[1][6]);
        acc[0][7] = fmaf(a0, wb.w, acc[0][7]); acc[1][7] = fmaf(a1, wb.w, acc[1][7]);
    }
    #pragma unroll
    for (int i = 0; i < 2; ++i)
        #pragma unroll
        for (int j = 0; j < 8; ++j)
            H[rowg * 2 + i][colg * 8 + j] = fmaxf(acc[i][j], 0.f);
    __syncthreads();

    // ---- GEMM2: out = H(32x128) @ W2(128x128) + b2
    const float* W2  = &rule_W2[(size_t)rule * 128 * 128 + colg * 8];
    const float* b2p = &rule_b2[rule * 128 + colg * 8];
    #pragma unroll
    for (int j = 0; j < 8; ++j) { acc[0][j] = b2p[j]; acc[1][j] = b2p[j]; }
    #pragma unroll 4
    for (int k = 0; k < 128; ++k) {
        float a0 = H[rowg * 2][k], a1 = H[rowg * 2 + 1][k];
        const float4 wa = *(const float4*)&W2[k * 128];
        const float4 wb = *(const float4*)&W2[k * 128 + 4];
        acc[0][0] = fmaf(a0, wa.x, acc[0][0]); acc[1][0] = fmaf(a1, wa.x, acc[1][0]);
        acc[0][1] = fmaf(a0, wa.y, acc[0][1]); acc[1][1] = fmaf(a1, wa.y, acc[1][1]);
        acc[0][2] = fmaf(a0, wa.z, acc[0][2]); acc[1][2] = fmaf(a1, wa.z, acc[1][2]);
        acc[0][3] = fmaf(a0, wa.w, acc[0][3]); acc[1][3] = fmaf(a1, wa.w, acc[1][3]);
        acc[0][4] = fmaf(a0, wb.x, acc[0][4]); acc[1][4] = fmaf(a1, wb.x, acc[1][4]);
        acc[0][5] = fmaf(a0, wb.y, acc[0][5]); acc[1][5] = fmaf(a1, wb.y, acc[1][5]);
        acc[0][6] = fmaf(a0, wb.z, acc[0][6]); acc[1][6] = fmaf(a1, wb.z, acc[1][6]);
        acc[0][7] = fmaf(a0, wb.w, acc[0][7]); acc[1][7] = fmaf(a1, wb.w, acc[1][7]);
    }
    __syncthreads();   // all LDS reads of this phase done; safe to overwrite A
    #pragma unroll
    for (int i = 0; i < 2; ++i)
        #pragma unroll
        for (int j = 0; j < 8; ++j)
            A[rowg * 2 + i][colg * 8 + j] = acc[i][j];
    __syncthreads();

    // ---- decoder: x3 = relu(out @ dec_w1 + dec_b1) @ dec_w2 + dec_b2
    const int lane = tid & 63;
    const int wv   = tid >> 6;            // wave 0..3, elements wv*8..+8
    const int e1   = min(wv * 8 + 8, nelem);
    for (int e = wv * 8; e < e1; ++e) {
        float hd = dec_b1[lane];
        #pragma unroll 8
        for (int d = 0; d < 128; ++d)
            hd = fmaf(A[e][d], dec_w1[d * 64 + lane], hd);
        hd = fmaxf(hd, 0.f);
        float v = hd * dec_w2[lane];
        #pragma unroll
        for (int off = 32; off; off >>= 1) v += __shfl_down(v, off);
        if (lane == 0) out[gi_s[e]] = v + dec_b2[0];
    }
}

extern "C" void kernel_launch(void* const* d_in, const int* in_sizes, int n_in,
                              void* d_out, int out_size, void* d_ws, size_t ws_size,
                              hipStream_t stream)
{
    const float* op1        = (const float*)d_in[0];
    const float* op2        = (const float*)d_in[1];
    const int*   opr        = (const int*)  d_in[2];
    const float* enc_op_w1  = (const float*)d_in[3];
    const float* enc_op_b1  = (const float*)d_in[4];
    const float* enc_op_w2  = (const float*)d_in[5];
    const float* enc_op_b2  = (const float*)d_in[6];
    const float* enc_opr_w1 = (const float*)d_in[7];
    const float* enc_opr_b1 = (const float*)d_in[8];
    const float* enc_opr_w2 = (const float*)d_in[9];
    const float* enc_opr_b2 = (const float*)d_in[10];
    const float* dec_w1     = (const float*)d_in[11];
    const float* dec_b1     = (const float*)d_in[12];
    const float* dec_w2     = (const float*)d_in[13];
    const float* dec_b2     = (const float*)d_in[14];
    const float* rules_emb  = (const float*)d_in[15];
    const float* rule_W1    = (const float*)d_in[16];
    const float* rule_b1    = (const float*)d_in[17];
    const float* rule_W2    = (const float*)d_in[18];
    const float* rule_b2    = (const float*)d_in[19];
    const float* s1_q_w     = (const float*)d_in[20];
    const float* s1_q_b     = (const float*)d_in[21];
    const float* s1_k_w     = (const float*)d_in[22];
    const float* s1_k_b     = (const float*)d_in[23];
    const float* s2_q_w     = (const float*)d_in[24];
    const float* s2_q_b     = (const float*)d_in[25];
    const float* s2_k_w     = (const float*)d_in[26];
    const float* s2_k_b     = (const float*)d_in[27];

    float* out = (float*)d_out;
    const int B = in_sizes[0];

    // workspace layout
    int*   cnt       = (int*)d_ws;
    int*   bucket    = cnt + 16;
    float* fbase     = (float*)(bucket + 16 * B);
    float* read1     = fbase;          // 512
    float* read2_all = fbase + 512;    // 512
    float* w1ope     = fbase + 1024;   // 96 (pad to 128)
    float* var_pc    = fbase + 1152;   // B*256

    setup_kernel<<<1, 256, 0, stream>>>(
        rules_emb, s1_k_w, s1_k_b, s2_k_w, s2_k_b,
        enc_opr_w1, enc_opr_b1, enc_opr_w2, enc_opr_b2,
        s1_q_w, s1_q_b, cnt, read1, read2_all, w1ope);

    stage1_kernel<<<B / 4, 256, 0, stream>>>(
        op1, op2, opr, enc_op_w1, enc_op_b1, enc_op_w2, enc_op_b2,
        s1_q_w, s1_q_b, s2_q_w, s2_q_b,
        read1, read2_all, w1ope, cnt, bucket, var_pc, B);

    dim3 g2((B + TB - 1) / TB, 16);
    stage2_kernel<<<g2, 256, 0, stream>>>(
        rule_W1, rule_b1, rule_W2, rule_b2,
        dec_w1, dec_b1, dec_w2, dec_b2,
        cnt, bucket, var_pc, out, B);
}

// Round 5
// 232.366 us; speedup vs baseline: 1.4226x; 1.4226x over previous
//
#include <hip/hip_runtime.h>
#include <math.h>

// ---------------------------------------------------------------------------
// ArithmeticNps: B=16384, CV=128, CR=64, NR=16, CM_RULE=128
//   setupA : zero padded rule counters; precompute read1[16][32],
//            read2[16][2][16], w1ope[3][32]  (bitwise same math as the
//            round-3 version that passed).
//   setupB : fold encoder w2 into rule_W1: W1h[r] (128x128), b1h[r].
//            Post-argmax continuous path only -> rounding-tolerant.
//   stage1 : 32 elems/block, 256 thr. Explicit h -> x -> write1/write2 ->
//            scores with fmaf order identical to round 3 (argmax decisions
//            bitwise-stable). Writes var_h=[h_p|h_c] (128 f/elem).
//            Bucketing: LDS histogram + ONE padded global atomic per rule
//            (fixes the 210us single-cache-line atomic serialization).
//   stage2 : per (rule, 32 elems): GEMM1 K=128 (W1h) + GEMM2 + fused decoder.
// NOTE: bucket must be 16*B ints — round 4 under-allocated it (B) and
// bucket writes for rule>=1 corrupted the float workspace. Fixed.
// ---------------------------------------------------------------------------

#define OFF_READ1 0        // 512
#define OFF_READ2 512      // 512
#define OFF_W1OPE 1024     // 96 (pad to 128)
#define OFF_W1H   1152     // 16*128*128 = 262144
#define OFF_B1H   263296   // 16*128 = 2048
#define OFF_VARH  265344   // B*128

// ---------------------------------------------------------------------------
__global__ __launch_bounds__(256) void setupA(
    const float* __restrict__ rules_emb, const float* __restrict__ s1_k_w,
    const float* __restrict__ s1_k_b,   const float* __restrict__ s2_k_w,
    const float* __restrict__ s2_k_b,
    const float* __restrict__ enc_opr_w1, const float* __restrict__ enc_opr_b1,
    const float* __restrict__ enc_opr_w2, const float* __restrict__ enc_opr_b2,
    const float* __restrict__ s1_q_w, const float* __restrict__ s1_q_b,
    int* __restrict__ cnt, float* __restrict__ fws)
{
    const int t = threadIdx.x;
    if (t < 16) cnt[t * 32] = 0;   // padded counters: one per cache line

    __shared__ float ope_s[3 * 128];
    for (int idx = t; idx < 3 * 128; idx += 256) {
        int v = idx >> 7, c = idx & 127;
        float o = enc_opr_b2[c];
        for (int j = 0; j < 64; ++j) {
            float h = fmaxf(enc_opr_w1[v * 64 + j] + enc_opr_b1[j], 0.f);
            o = fmaf(h, enc_opr_w2[j * 128 + c], o);
        }
        ope_s[idx] = o;
    }
    __syncthreads();

    // w1ope[v][m]
    for (int idx = t; idx < 96; idx += 256) {
        int v = idx >> 5, m = idx & 31;
        float a = s1_q_b[m];
        for (int c = 0; c < 128; ++c)
            a = fmaf(ope_s[v * 128 + c], s1_q_w[c * 32 + m], a);
        fws[OFF_W1OPE + idx] = a;
    }
    // read1[n][m]
    for (int idx = t; idx < 512; idx += 256) {
        int n = idx >> 5;
        float a = s1_k_b[idx];
        for (int r = 0; r < 64; ++r)
            a = fmaf(rules_emb[n * 64 + r], s1_k_w[(n * 64 + r) * 32 + (idx & 31)], a);
        fws[OFF_READ1 + idx] = a;
    }
    // read2[r][n][m]
    for (int idx = t; idx < 512; idx += 256) {
        int r = idx >> 5, n = (idx >> 4) & 1, m = idx & 15;
        float a = s2_k_b[n * 16 + m];
        for (int j = 0; j < 64; ++j)
            a = fmaf(rules_emb[r * 64 + j], s2_k_w[(n * 64 + j) * 16 + m], a);
        fws[OFF_READ2 + idx] = a;
    }
}

// ---------------------------------------------------------------------------
// W1h[r][half*64+j][m] = sum_c w2[j][c] * rule_W1[r][half*128+c][m]
__global__ __launch_bounds__(256) void setupB(
    const float* __restrict__ enc_op_w2, const float* __restrict__ enc_op_b2,
    const float* __restrict__ rule_W1,   const float* __restrict__ rule_b1,
    float* __restrict__ fws)
{
    const int r = blockIdx.x, half = blockIdx.y;
    const int t = threadIdx.x;
    const int colg = t & 15, rowg = t >> 4;   // j = rowg*4..+4, m = colg*8..+8
    const float* W1src = &rule_W1[((size_t)r * 256 + half * 128) * 128];

    float acc[4][8];
    #pragma unroll
    for (int i = 0; i < 4; ++i)
        #pragma unroll
        for (int j = 0; j < 8; ++j) acc[i][j] = 0.f;

    #pragma unroll 2
    for (int c = 0; c < 128; ++c) {
        const float4 wa = *(const float4*)&W1src[c * 128 + colg * 8];
        const float4 wb = *(const float4*)&W1src[c * 128 + colg * 8 + 4];
        #pragma unroll
        for (int i = 0; i < 4; ++i) {
            float w = enc_op_w2[(rowg * 4 + i) * 128 + c];
            acc[i][0] = fmaf(w, wa.x, acc[i][0]); acc[i][1] = fmaf(w, wa.y, acc[i][1]);
            acc[i][2] = fmaf(w, wa.z, acc[i][2]); acc[i][3] = fmaf(w, wa.w, acc[i][3]);
            acc[i][4] = fmaf(w, wb.x, acc[i][4]); acc[i][5] = fmaf(w, wb.y, acc[i][5]);
            acc[i][6] = fmaf(w, wb.z, acc[i][6]); acc[i][7] = fmaf(w, wb.w, acc[i][7]);
        }
    }
    #pragma unroll
    for (int i = 0; i < 4; ++i)
        #pragma unroll
        for (int j = 0; j < 8; ++j)
            fws[OFF_W1H + r * 16384 + (half * 64 + rowg * 4 + i) * 128 + colg * 8 + j] = acc[i][j];

    // b1h[r][m] = b1[r][m] + sum_c b2[c]*(W1[c][m] + W1[128+c][m])
    if (half == 0 && t < 128) {
        const float* W1r = &rule_W1[(size_t)r * 256 * 128];
        float b = rule_b1[r * 128 + t];
        for (int c = 0; c < 128; ++c)
            b += enc_op_b2[c] * (W1r[c * 128 + t] + W1r[(128 + c) * 128 + t]);
        fws[OFF_B1H + r * 128 + t] = b;
    }
}

// ---------------------------------------------------------------------------
__global__ __launch_bounds__(256) void stage1(
    const float* __restrict__ op1, const float* __restrict__ op2,
    const int* __restrict__ opr,
    const float* __restrict__ enc_op_w1, const float* __restrict__ enc_op_b1,
    const float* __restrict__ enc_op_w2, const float* __restrict__ enc_op_b2,
    const float* __restrict__ s1_q_w,   const float* __restrict__ s1_q_b,
    const float* __restrict__ s2_q_w,   const float* __restrict__ s2_q_b,
    int* __restrict__ cnt, int* __restrict__ bucket,
    float* __restrict__ fws, int B)
{
    const int t = threadIdx.x;
    const int blk = blockIdx.x;

    __shared__ float h[32][132];      // [e][k*64+j]
    __shared__ float xh[32][132];     // x for current k (reused k=0 then k=1)
    __shared__ float w1l[32][64];     // write1 [e][k*32+m]
    __shared__ float w2l[32][32];     // write2 [e][k*16+m]
    __shared__ float read1_s[512];
    __shared__ float read2_s[512];
    __shared__ float w1ope_s[96];
    __shared__ float bvaln[32][17];   // per-(e,n) max over k
    __shared__ float part2[4][32];
    __shared__ float o1s[32], o2s[32];
    __shared__ int ops[32], idxr[32], idxp[32], idxc[32];
    __shared__ int lcnt[16], lpos[32], base[16];

    if (t < 32) { o1s[t] = op1[blk*32+t]; o2s[t] = op2[blk*32+t]; ops[t] = opr[blk*32+t]; }
    if (t < 16) lcnt[t] = 0;
    for (int i = t; i < 512; i += 256) read1_s[i] = fws[OFF_READ1 + i];
    for (int i = t; i < 512; i += 256) read2_s[i] = fws[OFF_READ2 + i];
    if (t < 96) w1ope_s[t] = fws[OFF_W1OPE + t];
    __syncthreads();

    // encoder hiddens h (exact: relu(fma))
    for (int i = t; i < 4096; i += 256) {
        int e = i >> 7, j = i & 127;
        if (j < 64) {
            h[e][j] = fmaxf(fmaf(o1s[e], enc_op_w1[j], enc_op_b1[j]), 0.f);
        } else {
            int j2 = j - 64;
            h[e][j] = fmaxf(fmaf(o2s[e], enc_op_w1[j2], enc_op_w1[64 + j2] + enc_op_b1[j2]), 0.f);
        }
    }
    __syncthreads();

    // per operand slot k: x = h_k @ w2 + b2 ; write1/write2 rows
    for (int k = 0; k < 2; ++k) {
        {   // x half: thread (e = t>>3, cb = t&7) computes 16 cols
            const int e = t >> 3, cb = t & 7;
            float acc[16];
            #pragma unroll
            for (int i = 0; i < 16; ++i) acc[i] = enc_op_b2[cb * 16 + i];
            const float* hrow = &h[e][k * 64];
            for (int j = 0; j < 64; ++j) {
                float hv = hrow[j];
                const float* wr = &enc_op_w2[j * 128 + cb * 16];
                #pragma unroll
                for (int i = 0; i < 16; ++i) acc[i] = fmaf(hv, wr[i], acc[i]);
            }
            #pragma unroll
            for (int i = 0; i < 16; ++i) xh[e][cb * 16 + i] = acc[i];
        }
        __syncthreads();
        {   // write1 (4 m's) + write2 (2 m's) per thread
            const int e = t >> 3, m8 = t & 7;
            float a1[4], a2[2];
            #pragma unroll
            for (int i = 0; i < 4; ++i) a1[i] = s1_q_b[m8 * 4 + i];
            #pragma unroll
            for (int i = 0; i < 2; ++i) a2[i] = s2_q_b[k * 16 + m8 * 2 + i];
            for (int c = 0; c < 128; ++c) {
                float xv = xh[e][c];
                #pragma unroll
                for (int i = 0; i < 4; ++i)
                    a1[i] = fmaf(xv, s1_q_w[c * 32 + m8 * 4 + i], a1[i]);
                #pragma unroll
                for (int i = 0; i < 2; ++i)
                    a2[i] = fmaf(xv, s2_q_w[(k * 128 + c) * 16 + m8 * 2 + i], a2[i]);
            }
            #pragma unroll
            for (int i = 0; i < 4; ++i) w1l[e][k * 32 + m8 * 4 + i] = a1[i];
            #pragma unroll
            for (int i = 0; i < 2; ++i) w2l[e][k * 16 + m8 * 2 + i] = a2[i];
        }
        __syncthreads();
    }

    // attent1 scores: per (e,n) max over k (idx_r = n regardless of k;
    // cross-n strict > ascending = first-occurrence flat argmax)
    #pragma unroll
    for (int pp = 0; pp < 2; ++pp) {
        int idx = t + pp * 256;
        int e = idx >> 4, n = idx & 15;
        float best = -INFINITY;
        #pragma unroll
        for (int k = 0; k < 2; ++k) {
            float a = 0.f;
            #pragma unroll 8
            for (int m = 0; m < 32; ++m)
                a = fmaf(read1_s[n * 32 + m], w1l[e][k * 32 + m], a);
            best = fmaxf(best, a);
        }
        {
            const float* w1row = &w1ope_s[ops[e] * 32];
            float a = 0.f;
            #pragma unroll 8
            for (int m = 0; m < 32; ++m)
                a = fmaf(read1_s[n * 32 + m], w1row[m], a);
            best = fmaxf(best, a);
        }
        bvaln[e][n] = best;
    }
    __syncthreads();

    if (t < 32) {
        float best = -INFINITY; int bn = 0;
        for (int n = 0; n < 16; ++n) {
            float v = bvaln[t][n];
            if (v > best) { best = v; bn = n; }
        }
        idxr[t] = bn;
    }
    __syncthreads();

    // attent2
    if (t < 128) {
        const int e = t & 31, nk = t >> 5;
        const int n = nk >> 1, kk = nk & 1;
        const int r = idxr[e];
        float a = 0.f;
        #pragma unroll
        for (int m = 0; m < 16; ++m)
            a = fmaf(read2_s[r * 32 + n * 16 + m], w2l[e][kk * 16 + m], a);
        part2[nk][e] = a;
    }
    __syncthreads();
    if (t < 32) {
        idxp[t] = (part2[1][t] > part2[0][t]) ? 1 : 0;
        idxc[t] = (part2[3][t] > part2[2][t]) ? 1 : 0;
    }
    __syncthreads();

    // var_h[e] = [h_p(64) | h_c(64)]
    for (int i = t; i < 1024; i += 256) {
        int e = i >> 5, v4 = i & 31;
        int sel = (v4 < 16) ? idxp[e] : idxc[e];
        float4 val = *(const float4*)&h[e][sel * 64 + (v4 & 15) * 4];
        *(float4*)&fws[OFF_VARH + (size_t)(blk * 32 + e) * 128 + v4 * 4] = val;
    }

    // bucketing: LDS histogram -> one padded global atomic per rule
    if (t < 32) lpos[t] = atomicAdd(&lcnt[idxr[t]], 1);
    __syncthreads();
    if (t < 16 && lcnt[t] > 0) base[t] = atomicAdd(&cnt[t * 32], lcnt[t]);
    __syncthreads();
    if (t < 32) {
        int r = idxr[t];
        bucket[r * B + base[r] + lpos[t]] = blk * 32 + t;
    }
}

// ---------------------------------------------------------------------------
__global__ __launch_bounds__(256) void stage2(
    const float* __restrict__ rule_W2, const float* __restrict__ rule_b2,
    const float* __restrict__ dec_w1,  const float* __restrict__ dec_b1,
    const float* __restrict__ dec_w2,  const float* __restrict__ dec_b2,
    const int* __restrict__ cnt, const int* __restrict__ bucket,
    const float* __restrict__ fws, float* __restrict__ out, int B)
{
    const int rule  = blockIdx.y;
    const int start = blockIdx.x * 32;
    const int count = cnt[rule * 32];
    if (start >= count) return;
    const int nelem = min(32, count - start);
    const int t = threadIdx.x;

    __shared__ float A[32][132];
    __shared__ float H[32][132];
    __shared__ int gi_s[32];

    if (t < 32) gi_s[t] = bucket[rule * B + start + ((t < nelem) ? t : 0)];
    __syncthreads();
    for (int i = t; i < 32 * 32; i += 256) {
        int e = i >> 5, v = i & 31;
        *(float4*)&A[e][v * 4] = *(const float4*)&fws[OFF_VARH + (size_t)gi_s[e] * 128 + v * 4];
    }
    __syncthreads();

    const int colg = t & 15, rowg = t >> 4;

    // GEMM1: H = relu([h_p,h_c](32x128) @ W1h[rule](128x128) + b1h[rule])
    const float* W1  = &fws[OFF_W1H + rule * 16384 + colg * 8];
    const float* b1p = &fws[OFF_B1H + rule * 128 + colg * 8];
    float acc[2][8];
    #pragma unroll
    for (int j = 0; j < 8; ++j) { acc[0][j] = b1p[j]; acc[1][j] = b1p[j]; }
    #pragma unroll 4
    for (int k = 0; k < 128; ++k) {
        float a0 = A[rowg * 2][k], a1 = A[rowg * 2 + 1][k];
        const float4 wa = *(const float4*)&W1[k * 128];
        const float4 wb = *(const float4*)&W1[k * 128 + 4];
        acc[0][0] = fmaf(a0, wa.x, acc[0][0]); acc[1][0] = fmaf(a1, wa.x, acc[1][0]);
        acc[0][1] = fmaf(a0, wa.y, acc[0][1]); acc[1][1] = fmaf(a1, wa.y, acc[1][1]);
        acc[0][2] = fmaf(a0, wa.z, acc[0][2]); acc[1][2] = fmaf(a1, wa.z, acc[1][2]);
        acc[0][3] = fmaf(a0, wa.w, acc[0][3]); acc[1][3] = fmaf(a1, wa.w, acc[1][3]);
        acc[0][4] = fmaf(a0, wb.x, acc[0][4]); acc[1][4] = fmaf(a1, wb.x, acc[1][4]);
        acc[0][5] = fmaf(a0, wb.y, acc[0][5]); acc[1][5] = fmaf(a1, wb.y, acc[1][5]);
        acc[0][6] = fmaf(a0, wb.z, acc[0][6]); acc[1][6] = fmaf(a1, wb.z, acc[1][6]);
        acc[0][7] = fmaf(a0, wb.w, acc[0][7]); acc[1][7] = fmaf(a1, wb.w, acc[1][7]);
    }
    #pragma unroll
    for (int i = 0; i < 2; ++i)
        #pragma unroll
        for (int j = 0; j < 8; ++j)
            H[rowg * 2 + i][colg * 8 + j] = fmaxf(acc[i][j], 0.f);
    __syncthreads();

    // GEMM2: out_all = H(32x128) @ W2[rule](128x128) + b2[rule]
    const float* W2  = &rule_W2[(size_t)rule * 128 * 128 + colg * 8];
    const float* b2p = &rule_b2[rule * 128 + colg * 8];
    #pragma unroll
    for (int j = 0; j < 8; ++j) { acc[0][j] = b2p[j]; acc[1][j] = b2p[j]; }
    #pragma unroll 4
    for (int k = 0; k < 128; ++k) {
        float a0 = H[rowg * 2][k], a1 = H[rowg * 2 + 1][k];
        const float4 wa = *(const float4*)&W2[k * 128];
        const float4 wb = *(const float4*)&W2[k * 128 + 4];
        acc[0][0] = fmaf(a0, wa.x, acc[0][0]); acc[1][0] = fmaf(a1, wa.x, acc[1][0]);
        acc[0][1] = fmaf(a0, wa.y, acc[0][1]); acc[1][1] = fmaf(a1, wa.y, acc[1][1]);
        acc[0][2] = fmaf(a0, wa.z, acc[0][2]); acc[1][2] = fmaf(a1, wa.z, acc[1][2]);
        acc[0][3] = fmaf(a0, wa.w, acc[0][3]); acc[1][3] = fmaf(a1, wa.w, acc[1][3]);
        acc[0][4] = fmaf(a0, wb.x, acc[0][4]); acc[1][4] = fmaf(a1, wb.x, acc[1][4]);
        acc[0][5] = fmaf(a0, wb.y, acc[0][5]); acc[1][5] = fmaf(a1, wb.y, acc[1][5]);
        acc[0][6] = fmaf(a0, wb.z, acc[0][6]); acc[1][6] = fmaf(a1, wb.z, acc[1][6]);
        acc[0][7] = fmaf(a0, wb.w, acc[0][7]); acc[1][7] = fmaf(a1, wb.w, acc[1][7]);
    }
    __syncthreads();   // all A reads done; safe to overwrite
    #pragma unroll
    for (int i = 0; i < 2; ++i)
        #pragma unroll
        for (int j = 0; j < 8; ++j)
            A[rowg * 2 + i][colg * 8 + j] = acc[i][j];
    __syncthreads();

    // decoder: relu(out @ dec_w1 + dec_b1) @ dec_w2 + dec_b2
    const int lane = t & 63;
    const int wv   = t >> 6;
    const int e1   = min(wv * 8 + 8, nelem);
    for (int e = wv * 8; e < e1; ++e) {
        float hd = dec_b1[lane];
        #pragma unroll 8
        for (int d = 0; d < 128; ++d)
            hd = fmaf(A[e][d], dec_w1[d * 64 + lane], hd);
        hd = fmaxf(hd, 0.f);
        float v = hd * dec_w2[lane];
        #pragma unroll
        for (int off = 32; off; off >>= 1) v += __shfl_down(v, off);
        if (lane == 0) out[gi_s[e]] = v + dec_b2[0];
    }
}

// ---------------------------------------------------------------------------
extern "C" void kernel_launch(void* const* d_in, const int* in_sizes, int n_in,
                              void* d_out, int out_size, void* d_ws, size_t ws_size,
                              hipStream_t stream)
{
    const float* op1        = (const float*)d_in[0];
    const float* op2        = (const float*)d_in[1];
    const int*   opr        = (const int*)  d_in[2];
    const float* enc_op_w1  = (const float*)d_in[3];
    const float* enc_op_b1  = (const float*)d_in[4];
    const float* enc_op_w2  = (const float*)d_in[5];
    const float* enc_op_b2  = (const float*)d_in[6];
    const float* enc_opr_w1 = (const float*)d_in[7];
    const float* enc_opr_b1 = (const float*)d_in[8];
    const float* enc_opr_w2 = (const float*)d_in[9];
    const float* enc_opr_b2 = (const float*)d_in[10];
    const float* dec_w1     = (const float*)d_in[11];
    const float* dec_b1     = (const float*)d_in[12];
    const float* dec_w2     = (const float*)d_in[13];
    const float* dec_b2     = (const float*)d_in[14];
    const float* rules_emb  = (const float*)d_in[15];
    const float* rule_W1    = (const float*)d_in[16];
    const float* rule_b1    = (const float*)d_in[17];
    const float* rule_W2    = (const float*)d_in[18];
    const float* rule_b2    = (const float*)d_in[19];
    const float* s1_q_w     = (const float*)d_in[20];
    const float* s1_q_b     = (const float*)d_in[21];
    const float* s1_k_w     = (const float*)d_in[22];
    const float* s1_k_b     = (const float*)d_in[23];
    const float* s2_q_w     = (const float*)d_in[24];
    const float* s2_q_b     = (const float*)d_in[25];
    const float* s2_k_w     = (const float*)d_in[26];
    const float* s2_k_b     = (const float*)d_in[27];

    float* out = (float*)d_out;
    const int B = in_sizes[0];

    int*   cnt    = (int*)d_ws;                 // 16*32 padded counters
    int*   bucket = cnt + 16 * 32;              // 16*B  (FIX: full size!)
    float* fws    = (float*)(bucket + 16 * B);  // float region (16B aligned)

    setupB<<<dim3(16, 2), 256, 0, stream>>>(enc_op_w2, enc_op_b2, rule_W1, rule_b1, fws);

    setupA<<<1, 256, 0, stream>>>(
        rules_emb, s1_k_w, s1_k_b, s2_k_w, s2_k_b,
        enc_opr_w1, enc_opr_b1, enc_opr_w2, enc_opr_b2,
        s1_q_w, s1_q_b, cnt, fws);

    stage1<<<B / 32, 256, 0, stream>>>(
        op1, op2, opr, enc_op_w1, enc_op_b1, enc_op_w2, enc_op_b2,
        s1_q_w, s1_q_b, s2_q_w, s2_q_b, cnt, bucket, fws, B);

    stage2<<<dim3(B / 32, 16), 256, 0, stream>>>(
        rule_W2, rule_b2, dec_w1, dec_b1, dec_w2, dec_b2,
        cnt, bucket, fws, out, B);
}